// Round 5
// baseline (247.919 us; speedup 1.0000x reference)
//
#include <hip/hip_runtime.h>
#include <stdint.h>

#define B_ROWS 4096
#define L_FEAT 256
#define VOCAB  8192

#define BM 128
#define BN 128
#define NTILE 32      // 4096/128
#define NTRI  528     // NTILE*(NTILE+1)/2
#define NKW   256     // 32-bit words per row (8192/32)
#define KWSLAB 128    // k-words per K-slab (split-K = 2)
#define LDST  80      // LDS bytes per row: 64 data + 16 pad (conflict-free)

typedef __attribute__((ext_vector_type(4))) int intx4;

__device__ __forceinline__ int tri_index(int a, int b) {  // a<=b
  return a * NTILE - (a * (a - 1)) / 2 + (b - a);
}

// Expand 32 presence bits -> 32 bytes in {0x00, 0x80} and store to LDS.
// Per word: ((rep & posmask) + 0x7f7f7f7f) & 0x80808080 — no cross-byte carry
// (max per-byte sum 0xff), bit7 set iff the position's bit was set.
__device__ __forceinline__ void expand_store(unsigned int x, void* dst) {
  uint4 v0, v1;
  unsigned int rep;
  rep = __builtin_amdgcn_perm(x, x, 0x00000000u);  // byte0 replicated
  v0.x = ((rep & 0x08040201u) + 0x7f7f7f7fu) & 0x80808080u;  // bits 0..3
  v0.y = ((rep & 0x80402010u) + 0x7f7f7f7fu) & 0x80808080u;  // bits 4..7
  rep = __builtin_amdgcn_perm(x, x, 0x01010101u);  // byte1
  v0.z = ((rep & 0x08040201u) + 0x7f7f7f7fu) & 0x80808080u;
  v0.w = ((rep & 0x80402010u) + 0x7f7f7f7fu) & 0x80808080u;
  rep = __builtin_amdgcn_perm(x, x, 0x02020202u);  // byte2
  v1.x = ((rep & 0x08040201u) + 0x7f7f7f7fu) & 0x80808080u;
  v1.y = ((rep & 0x80402010u) + 0x7f7f7f7fu) & 0x80808080u;
  rep = __builtin_amdgcn_perm(x, x, 0x03030303u);  // byte3
  v1.z = ((rep & 0x08040201u) + 0x7f7f7f7fu) & 0x80808080u;
  v1.w = ((rep & 0x80402010u) + 0x7f7f7f7fu) & 0x80808080u;
  *(uint4*)dst = v0;
  *((uint4*)dst + 1) = v1;
}

// ---------------- kernel 1: zero packed P (4 MB) -----------------------------
__global__ void zero_kernel(uint4* __restrict__ p, int n16) {
  int i = blockIdx.x * blockDim.x + threadIdx.x;
  const int stride = gridDim.x * blockDim.x;
  const uint4 z = make_uint4(0u, 0u, 0u, 0u);
  for (; i < n16; i += stride) p[i] = z;
}

// ---------------- kernel 2: scatter bits -------------------------------------
// Tiled packed layout: word L(r, kw) = ((r>>7)*NKW + kw)*128 + (r&127),
// bit v&31 — makes gemm staging reads contiguous per (rowblock, kw).
__global__ void scatter_kernel(const int* __restrict__ f,
                               unsigned int* __restrict__ Pk) {
  const int id  = blockIdx.x * 256 + threadIdx.x;
  const int r   = id >> 8;
  const int v   = f[id];
  const int idx = ((r >> 7) * NKW + (v >> 5)) * 128 + (r & 127);
  atomicOr(&Pk[idx], 1u << (v & 31));
}

// ---------------- kernel 3: split-K i8 GEMM from packed bits -----------------
// grid (528, 2): x = triangle tile, y = K-slab. 128x128 tile, 64 iters of
// BK=64 (2 packed words/row/iter). Staging: coalesced word loads -> VALU
// expand to {0,0x80} bytes -> LDS (stride 80, conflict-free) -> i8 MFMA.
// acc = inter * 16384; partial u16 = acc >> 14.
__global__ __launch_bounds__(256) void gemm_kernel(
    const unsigned int* __restrict__ Pk,
    unsigned short* __restrict__ scratch) {
  const int tile = blockIdx.x, slab = blockIdx.y;
  int t = tile, a = 0, rem = NTILE;
  while (t >= rem) { t -= rem; ++a; --rem; }
  const int b = a + t;

  __shared__ __align__(16) unsigned char As[BM * LDST];  // 10 KB
  __shared__ __align__(16) unsigned char Bs[BN * LDST];  // 10 KB

  const int tid  = threadIdx.x;
  const int wave = tid >> 6, lane = tid & 63;
  const int wm = wave >> 1, wn = wave & 1;
  const int col16 = lane & 15, quad = lane >> 4;

  intx4 acc[4][4];
  #pragma unroll
  for (int i = 0; i < 4; ++i)
    #pragma unroll
    for (int j = 0; j < 4; ++j) acc[i][j] = (intx4){0, 0, 0, 0};

  // staging assignment: thread tid handles row rl = tid&127, k-word h = tid>>7
  const int rl = tid & 127;
  const int h  = tid >> 7;
  const unsigned int* pa = Pk + (size_t)(a * NKW + slab * KWSLAB + h) * 128 + rl;
  const unsigned int* pb = Pk + (size_t)(b * NKW + slab * KWSLAB + h) * 128 + rl;
  unsigned char* wA = &As[rl * LDST + h * 32];
  unsigned char* wB = &Bs[rl * LDST + h * 32];

  for (int it = 0; it < KWSLAB / 2; ++it) {
    const unsigned int xa = pa[it * 256];   // +2 k-words = 256 words
    const unsigned int xb = pb[it * 256];
    __syncthreads();                        // prior iter finished reading LDS
    expand_store(xa, wA);
    expand_store(xb, wB);
    __syncthreads();

    intx4 af[4], bf[4];
    #pragma unroll
    for (int tm = 0; tm < 4; ++tm)
      af[tm] = *(const intx4*)&As[(wm * 64 + tm * 16 + col16) * LDST + quad * 16];
    #pragma unroll
    for (int tn = 0; tn < 4; ++tn)
      bf[tn] = *(const intx4*)&Bs[(wn * 64 + tn * 16 + col16) * LDST + quad * 16];
    #pragma unroll
    for (int tm = 0; tm < 4; ++tm)
      #pragma unroll
      for (int tn = 0; tn < 4; ++tn)
        acc[tm][tn] = __builtin_amdgcn_mfma_i32_16x16x64_i8(
            af[tm], bf[tn], acc[tm][tn], 0, 0, 0);
  }

  unsigned short* pp = scratch + ((size_t)slab * NTRI + tile) * (BM * BN);
  #pragma unroll
  for (int tm = 0; tm < 4; ++tm)
    #pragma unroll
    for (int tn = 0; tn < 4; ++tn) {
      const int colL = wn * 64 + tn * 16 + col16;
      #pragma unroll
      for (int r = 0; r < 4; ++r) {
        const int rowL = wm * 64 + tm * 16 + quad * 4 + r;
        pp[rowL * BN + colL] =
            (unsigned short)(((unsigned int)acc[tm][tn][r]) >> 14);
      }
    }
}

// ---------------- kernel 4: fused combine + Jaccard + mirror -----------------
// One block per triangle tile (a<=b). Sums the two slab partials inline
// (packed u16 adds, each half <= 256 so no carry). Sizes from diag tiles.
__global__ __launch_bounds__(256) void epilogue_kernel(
    const unsigned short* __restrict__ scratch,
    float* __restrict__ out) {
  int t = blockIdx.x, a = 0, rem = NTILE;
  while (t >= rem) { t -= rem; ++a; --rem; }
  const int b = a + t;
  const size_t SL = (size_t)NTRI * (BM * BN);  // slab stride (elements)

  __shared__ float rowsz[128], colsz[128];
  __shared__ float ldsT[64 * 65];  // transpose staging

  const int tid = threadIdx.x;
  {
    const unsigned short* dA = scratch + (size_t)tri_index(a, a) * (BM * BN);
    const unsigned short* dB = scratch + (size_t)tri_index(b, b) * (BM * BN);
    if (tid < 128) {
      const int d = tid * 129;
      rowsz[tid] = (float)((unsigned int)dA[d] + (unsigned int)dA[d + SL]);
    } else {
      const int d = (tid - 128) * 129;
      colsz[tid - 128] =
          (float)((unsigned int)dB[d] + (unsigned int)dB[d + SL]);
    }
  }
  __syncthreads();

  const unsigned short* u = scratch + (size_t)tri_index(a, b) * (BM * BN);

  // phase 1: upper tile (a,b) — coalesced uint2 reads x2, float4 writes
  {
    const int c4 = (tid & 31) * 4;
    const int rq = tid >> 5;  // 0..7
    #pragma unroll
    for (int rr = 0; rr < 16; ++rr) {
      const int r = rr * 8 + rq;
      const uint2 p0 = *(const uint2*)&u[r * BN + c4];
      const uint2 p1 = *(const uint2*)&u[r * BN + c4 + SL];
      const unsigned int sx = p0.x + p1.x, sy = p0.y + p1.y;
      const float si = rowsz[r];
      float4 o;
      float iv;
      iv = (float)(sx & 0xFFFFu); o.x = -iv / (si + colsz[c4]     - iv);
      iv = (float)(sx >> 16);     o.y = -iv / (si + colsz[c4 + 1] - iv);
      iv = (float)(sy & 0xFFFFu); o.z = -iv / (si + colsz[c4 + 2] - iv);
      iv = (float)(sy >> 16);     o.w = -iv / (si + colsz[c4 + 3] - iv);
      *(float4*)&out[(size_t)(a * BM + r) * B_ROWS + b * BN + c4] = o;
    }
  }

  // phase 2: mirror tile (b,a) via LDS transpose per 64x64 quadrant
  if (b > a) {
    const int c4q = (tid & 15) * 4;
    const int rqq = tid >> 4;  // 0..15
    #pragma unroll
    for (int q = 0; q < 4; ++q) {
      const int qa = q >> 1, qb = q & 1;
      __syncthreads();
      #pragma unroll
      for (int rr = 0; rr < 4; ++rr) {
        const int r = rr * 16 + rqq;  // src row-local 0..63
        const int base = (qa * 64 + r) * BN + qb * 64 + c4q;
        const uint2 p0 = *(const uint2*)&u[base];
        const uint2 p1 = *(const uint2*)&u[base + SL];
        const unsigned int sx = p0.x + p1.x, sy = p0.y + p1.y;
        const float si = rowsz[qa * 64 + r];
        float iv;
        iv = (float)(sx & 0xFFFFu);
        ldsT[(c4q + 0) * 65 + r] = -iv / (si + colsz[qb * 64 + c4q]     - iv);
        iv = (float)(sx >> 16);
        ldsT[(c4q + 1) * 65 + r] = -iv / (si + colsz[qb * 64 + c4q + 1] - iv);
        iv = (float)(sy & 0xFFFFu);
        ldsT[(c4q + 2) * 65 + r] = -iv / (si + colsz[qb * 64 + c4q + 2] - iv);
        iv = (float)(sy >> 16);
        ldsT[(c4q + 3) * 65 + r] = -iv / (si + colsz[qb * 64 + c4q + 3] - iv);
      }
      __syncthreads();
      #pragma unroll
      for (int rr = 0; rr < 4; ++rr) {
        const int e = rr * 16 + rqq;  // dest row-local (= src col)
        float4 o;
        o.x = ldsT[e * 65 + c4q];
        o.y = ldsT[e * 65 + c4q + 1];
        o.z = ldsT[e * 65 + c4q + 2];
        o.w = ldsT[e * 65 + c4q + 3];
        *(float4*)&out[(size_t)(b * BM + qb * 64 + e) * B_ROWS +
                       a * BN + qa * 64 + c4q] = o;
      }
    }
  }
}

// ---------------- launcher ---------------------------------------------------
extern "C" void kernel_launch(void* const* d_in, const int* in_sizes, int n_in,
                              void* d_out, int out_size, void* d_ws, size_t ws_size,
                              hipStream_t stream) {
  const int* features = (const int*)d_in[0];
  float* out = (float*)d_out;
  // ws layout: [Pk packed 4MB][scratch u16 partials 2 x 528 x 32KB = 34.6MB]
  unsigned int* Pk = (unsigned int*)d_ws;
  unsigned short* scratch =
      (unsigned short*)((char*)d_ws + (size_t)(NTILE * NKW * 128) * 4);

  zero_kernel<<<512, 256, 0, stream>>>((uint4*)Pk, NTILE * NKW * 128 / 4);
  scatter_kernel<<<(B_ROWS * L_FEAT) / 256, 256, 0, stream>>>(features, Pk);
  gemm_kernel<<<dim3(NTRI, 2), 256, 0, stream>>>(Pk, scratch);
  epilogue_kernel<<<NTRI, 256, 0, stream>>>(scratch, out);
}

// Round 6
// 241.107 us; speedup vs baseline: 1.0283x; 1.0283x over previous
//
#include <hip/hip_runtime.h>
#include <stdint.h>

#define B_ROWS 4096
#define L_FEAT 256
#define VOCAB  8192

#define NTILE 32      // 4096/128
#define NTRI  528     // NTILE*(NTILE+1)/2
#define NKP   128     // uint2 (64-bit) k-groups per row (8192/64)

typedef __attribute__((ext_vector_type(4))) int intx4;

// ---------------- kernel 1: zero packed P (4 MB) -----------------------------
__global__ void zero_kernel(uint4* __restrict__ p, int n16) {
  int i = blockIdx.x * blockDim.x + threadIdx.x;
  const int stride = gridDim.x * blockDim.x;
  const uint4 z = make_uint4(0u, 0u, 0u, 0u);
  for (; i < n16; i += stride) p[i] = z;
}

// ---------------- kernel 2: scatter bits -------------------------------------
// uint2-tiled packed layout: element idx2(r, kp) = ((r>>7)*NKP + kp)*128 + (r&127)
// (kp = 64-bit k-group). In u32 units: idx2*2 + ((v>>5)&1).
__global__ void scatter_kernel(const int* __restrict__ f,
                               unsigned int* __restrict__ Pk) {
  const int id = blockIdx.x * 256 + threadIdx.x;
  const int r  = id >> 8;
  const int v  = f[id];
  const int w  = (((r >> 7) * NKP + (v >> 6)) * 128 + (r & 127)) * 2 +
                 ((v >> 5) & 1);
  atomicOr(&Pk[w], 1u << (v & 31));
}

// ---------------- kernel 3: per-row set sizes (popcount of packed rows) ------
__global__ void sizes_kernel(const uint2* __restrict__ Pk2,
                             float* __restrict__ sizes) {
  const int g  = blockIdx.x;          // row block 0..31
  const int rl = threadIdx.x & 127;
  const int h  = threadIdx.x >> 7;    // k-half
  const uint2* p = Pk2 + ((size_t)g * NKP + h * 64) * 128 + rl;
  int cnt = 0;
  #pragma unroll 8
  for (int kp = 0; kp < 64; ++kp) {
    const uint2 v = p[(size_t)kp * 128];
    cnt += __popc(v.x) + __popc(v.y);
  }
  __shared__ int part[128];
  if (h == 0) part[rl] = cnt;
  __syncthreads();
  if (h == 1) sizes[g * 128 + rl] = (float)(part[rl] + cnt);
}

// Expand 16 packed bits (selected by lane's quad from a uint2) into a 16-byte
// i8 fragment with bytes in {0x00, 0x80}. (-128)*(-128)=16384 per match, so
// acc>>14 recovers the exact intersection count.
__device__ __forceinline__ intx4 expand16(uint2 v, bool hi, unsigned sel0,
                                          unsigned sel1) {
  const unsigned w  = hi ? v.y : v.x;
  const unsigned r0 = __builtin_amdgcn_perm(w, w, sel0);  // low byte of halfword
  const unsigned r1 = __builtin_amdgcn_perm(w, w, sel1);  // high byte
  intx4 f;
  f[0] = (int)(((r0 & 0x08040201u) + 0x7f7f7f7fu) & 0x80808080u);  // bits 0-3
  f[1] = (int)(((r0 & 0x80402010u) + 0x7f7f7f7fu) & 0x80808080u);  // bits 4-7
  f[2] = (int)(((r1 & 0x08040201u) + 0x7f7f7f7fu) & 0x80808080u);  // bits 8-11
  f[3] = (int)(((r1 & 0x80402010u) + 0x7f7f7f7fu) & 0x80808080u);  // bits 12-15
  return f;
}

// ---------------- kernel 4: register-direct i8 GEMM + fused Jaccard ----------
// One block per triangle tile (a<=b). 4 waves 2x2; each wave 64x64 via 4x4 of
// mfma_i32_16x16x64_i8. NO LDS / NO barriers in the K-loop: each lane loads
// its row's uint2 (one 128B line per 16-lane group, quads merge) and expands
// 16 bits -> 16-byte fragment in registers. Epilogue: u16 inter tile -> LDS,
// one barrier, coalesced float4 stores for upper + LDS-transposed mirror.
__global__ __launch_bounds__(256, 3) void gemm_kernel(
    const uint2* __restrict__ Pk2,
    const float* __restrict__ sizes,
    float* __restrict__ out) {
  int t = blockIdx.x, a = 0, rem = NTILE;
  while (t >= rem) { t -= rem; ++a; --rem; }
  const int b = a + t;

  const int tid  = threadIdx.x;
  const int wave = tid >> 6, lane = tid & 63;
  const int wm = wave >> 1, wn = wave & 1;
  const int col16 = lane & 15, quad = lane >> 4;

  // per-lane expansion constants
  const bool hi = (quad & 2) != 0;
  const unsigned sel0 = 0x01010101u * (unsigned)((quad & 1) * 2);
  const unsigned sel1 = sel0 + 0x01010101u;

  // per-lane row pointers (uint2 units); fragment rows at imm offsets tm*16
  const uint2* pa = Pk2 + (size_t)a * (NKP * 128) + wm * 64 + col16;
  const uint2* pb = Pk2 + (size_t)b * (NKP * 128) + wn * 64 + col16;

  intx4 acc[4][4];
  #pragma unroll
  for (int i = 0; i < 4; ++i)
    #pragma unroll
    for (int j = 0; j < 4; ++j) acc[i][j] = (intx4){0, 0, 0, 0};

  uint2 va[4], vb[4];
  #pragma unroll
  for (int m = 0; m < 4; ++m) { va[m] = pa[m * 16]; vb[m] = pb[m * 16]; }
  pa += 128; pb += 128;

  for (int it = 0; it < NKP; ++it) {
    // prefetch next k-group (last iter over-reads ~1.4KB into the sizes
    // region at Pk2+4MB — owned ws memory, value discarded)
    uint2 na[4], nb[4];
    #pragma unroll
    for (int m = 0; m < 4; ++m) { na[m] = pa[m * 16]; nb[m] = pb[m * 16]; }
    pa += 128; pb += 128;

    intx4 af[4];
    #pragma unroll
    for (int m = 0; m < 4; ++m) af[m] = expand16(va[m], hi, sel0, sel1);
    #pragma unroll
    for (int n = 0; n < 4; ++n) {
      const intx4 bf = expand16(vb[n], hi, sel0, sel1);
      #pragma unroll
      for (int m = 0; m < 4; ++m)
        acc[m][n] = __builtin_amdgcn_mfma_i32_16x16x64_i8(af[m], bf, acc[m][n],
                                                          0, 0, 0);
    }
    #pragma unroll
    for (int m = 0; m < 4; ++m) { va[m] = na[m]; vb[m] = nb[m]; }
  }

  // ---- fused epilogue ----
  __shared__ unsigned short tile[128][130];  // inter counts, +2 pad
  __shared__ float rsz[128], csz[128];

  if (tid < 128) rsz[tid] = sizes[a * 128 + tid];
  else           csz[tid - 128] = sizes[b * 128 + (tid - 128)];

  #pragma unroll
  for (int m = 0; m < 4; ++m)
    #pragma unroll
    for (int n = 0; n < 4; ++n) {
      const int col = wn * 64 + n * 16 + col16;
      #pragma unroll
      for (int r = 0; r < 4; ++r) {
        const int row = wm * 64 + m * 16 + quad * 4 + r;
        tile[row][col] = (unsigned short)(((unsigned int)acc[m][n][r]) >> 14);
      }
    }
  __syncthreads();

  // upper tile (a,b): float4 coalesced stores
  {
    const int c4 = (tid & 31) * 4;
    const int r0 = tid >> 5;
    #pragma unroll
    for (int rr = 0; rr < 16; ++rr) {
      const int r = rr * 8 + r0;
      const float si = rsz[r];
      float4 o;
      float iv;
      iv = (float)tile[r][c4];     o.x = -iv / (si + csz[c4]     - iv);
      iv = (float)tile[r][c4 + 1]; o.y = -iv / (si + csz[c4 + 1] - iv);
      iv = (float)tile[r][c4 + 2]; o.z = -iv / (si + csz[c4 + 2] - iv);
      iv = (float)tile[r][c4 + 3]; o.w = -iv / (si + csz[c4 + 3] - iv);
      *(float4*)&out[(size_t)(a * 128 + r) * B_ROWS + b * 128 + c4] = o;
    }
  }

  // mirror tile (b,a): transposed LDS reads, float4 coalesced stores
  if (b > a) {
    const int i4 = (tid & 31) * 4;  // source rows -> dest cols
    const int j0 = tid >> 5;
    #pragma unroll
    for (int rr = 0; rr < 16; ++rr) {
      const int jj = rr * 8 + j0;   // source col -> dest row
      const float sj = csz[jj];
      float4 o;
      float iv;
      iv = (float)tile[i4][jj];     o.x = -iv / (rsz[i4]     + sj - iv);
      iv = (float)tile[i4 + 1][jj]; o.y = -iv / (rsz[i4 + 1] + sj - iv);
      iv = (float)tile[i4 + 2][jj]; o.z = -iv / (rsz[i4 + 2] + sj - iv);
      iv = (float)tile[i4 + 3][jj]; o.w = -iv / (rsz[i4 + 3] + sj - iv);
      *(float4*)&out[(size_t)(b * 128 + jj) * B_ROWS + a * 128 + i4] = o;
    }
  }
}

// ---------------- launcher ---------------------------------------------------
extern "C" void kernel_launch(void* const* d_in, const int* in_sizes, int n_in,
                              void* d_out, int out_size, void* d_ws, size_t ws_size,
                              hipStream_t stream) {
  const int* features = (const int*)d_in[0];
  float* out = (float*)d_out;
  // ws layout: [Pk packed 4MB][sizes 16KB]
  unsigned int* Pk = (unsigned int*)d_ws;
  float* sizes = (float*)((char*)d_ws + (size_t)NTILE * NKP * 128 * 8);

  zero_kernel<<<512, 256, 0, stream>>>((uint4*)Pk, NTILE * NKP * 128 * 8 / 16);
  scatter_kernel<<<(B_ROWS * L_FEAT) / 256, 256, 0, stream>>>(features, Pk);
  sizes_kernel<<<NTILE, 256, 0, stream>>>((const uint2*)Pk, sizes);
  gemm_kernel<<<NTRI, 256, 0, stream>>>((const uint2*)Pk, sizes, out);
}